// Round 1
// baseline (350.358 us; speedup 1.0000x reference)
//
#include <hip/hip_runtime.h>
#include <math.h>

// Problem constants (from reference): B=32, H=1024, W=1024, N=100000
#define RD_H 1024
#define RD_W 1024
#define RD_N 100000
#define BDIM 256

__global__ void rd_zero_kernel(float* out) { out[0] = 0.0f; }

__global__ __launch_bounds__(BDIM) void rd_loss_kernel(
    const float* __restrict__ depth,   // (B, H, W) fp32 (leading singleton dim collapsed)
    const int*   __restrict__ xA,
    const int*   __restrict__ yA,
    const int*   __restrict__ xB,
    const int*   __restrict__ yB,
    const int*   __restrict__ ord,
    float* __restrict__ out,
    int total, float inv_total)
{
    int i = blockIdx.x * blockDim.x + threadIdx.x;
    float loss = 0.0f;
    if (i < total) {
        int b = i / RD_N;                       // batch index
        long base = (long)b * (RD_H * RD_W);
        int xa = xA[i], ya = yA[i];
        int xb = xB[i], yb = yB[i];
        float za = depth[base + (long)ya * RD_W + xa];
        float zb = depth[base + (long)yb * RD_W + xb];
        float diff = za - zb;
        float gt   = (float)(ord[i] - 1);       // in {-1, 0, 1}
        float mask = fabsf(gt);                 // {0, 1}
        // numerically-stable softplus(-gt*diff) = max(x,0) + log1p(exp(-|x|))
        float x  = -gt * diff;
        float sp = fmaxf(x, 0.0f) + log1pf(__expf(-fabsf(x)));
        loss = mask * sp + (1.0f - mask) * diff * diff;
    }

    // wave-64 shuffle reduction
    #pragma unroll
    for (int off = 32; off > 0; off >>= 1)
        loss += __shfl_down(loss, off, 64);

    __shared__ float wsum[BDIM / 64];
    int lane = threadIdx.x & 63;
    int wid  = threadIdx.x >> 6;
    if (lane == 0) wsum[wid] = loss;
    __syncthreads();

    if (threadIdx.x == 0) {
        float s = 0.0f;
        #pragma unroll
        for (int w = 0; w < BDIM / 64; ++w) s += wsum[w];
        atomicAdd(out, s * inv_total);   // pre-scaled partial: sum stays O(1)
    }
}

extern "C" void kernel_launch(void* const* d_in, const int* in_sizes, int n_in,
                              void* d_out, int out_size, void* d_ws, size_t ws_size,
                              hipStream_t stream) {
    const float* depth = (const float*)d_in[0];
    const int*   xA    = (const int*)d_in[1];
    const int*   yA    = (const int*)d_in[2];
    const int*   xB    = (const int*)d_in[3];
    const int*   yB    = (const int*)d_in[4];
    const int*   ord   = (const int*)d_in[5];
    float* out = (float*)d_out;

    int total = in_sizes[1];                 // B*N = 3,200,000
    float inv_total = 1.0f / (float)total;

    // d_out is poisoned to 0xAA before every timed launch — zero it first.
    rd_zero_kernel<<<1, 1, 0, stream>>>(out);

    int grid = (total + BDIM - 1) / BDIM;    // 12500 blocks
    rd_loss_kernel<<<grid, BDIM, 0, stream>>>(
        depth, xA, yA, xB, yB, ord, out, total, inv_total);
}

// Round 2
// 289.598 us; speedup vs baseline: 1.2098x; 1.2098x over previous
//
#include <hip/hip_runtime.h>
#include <math.h>

// Problem constants (from reference): B=32, H=1024, W=1024, N=100000
#define RD_H 1024
#define RD_W 1024
#define RD_N 100000
#define BDIM 256
#define UNROLL 8   // N % 8 == 0 -> all 8 points of a thread share one batch index

__global__ void rd_zero_kernel(float* out) { out[0] = 0.0f; }

__global__ __launch_bounds__(BDIM) void rd_loss_kernel(
    const float* __restrict__ depth,   // (B, H, W) fp32
    const int*   __restrict__ xA,
    const int*   __restrict__ yA,
    const int*   __restrict__ xB,
    const int*   __restrict__ yB,
    const int*   __restrict__ ord,
    float* __restrict__ out,
    int nthreads, float inv_total)
{
    int t = blockIdx.x * blockDim.x + threadIdx.x;
    float loss = 0.0f;
    if (t < nthreads) {
        int i0 = t * UNROLL;
        // All UNROLL consecutive points share one batch (RD_N % UNROLL == 0).
        int b = i0 / RD_N;
        const float* img = depth + (long)b * (RD_H * RD_W);

        // Vectorized, fully-coalesced index loads: 2x int4 per array.
        const int4* xA4 = (const int4*)(xA + i0);
        const int4* yA4 = (const int4*)(yA + i0);
        const int4* xB4 = (const int4*)(xB + i0);
        const int4* yB4 = (const int4*)(yB + i0);
        const int4* or4 = (const int4*)(ord + i0);
        int4 xa[2] = {xA4[0], xA4[1]};
        int4 ya[2] = {yA4[0], yA4[1]};
        int4 xb[2] = {xB4[0], xB4[1]};
        int4 yb[2] = {yB4[0], yB4[1]};
        int4 od[2] = {or4[0], or4[1]};

        const int* xap = (const int*)xa;
        const int* yap = (const int*)ya;
        const int* xbp = (const int*)xb;
        const int* ybp = (const int*)yb;
        const int* odp = (const int*)od;

        // Issue all 16 gathers before any use -> 16 loads in flight per thread.
        float za[UNROLL], zb[UNROLL];
        #pragma unroll
        for (int j = 0; j < UNROLL; ++j)
            za[j] = img[yap[j] * RD_W + xap[j]];
        #pragma unroll
        for (int j = 0; j < UNROLL; ++j)
            zb[j] = img[ybp[j] * RD_W + xbp[j]];

        #pragma unroll
        for (int j = 0; j < UNROLL; ++j) {
            float diff = za[j] - zb[j];
            float gt   = (float)(odp[j] - 1);   // {-1, 0, 1}
            float mask = fabsf(gt);             // {0, 1}
            // stable softplus(-gt*diff) = max(x,0) + log1p(exp(-|x|))
            float x  = -gt * diff;
            float sp = fmaxf(x, 0.0f) + log1pf(__expf(-fabsf(x)));
            loss += mask * sp + (1.0f - mask) * diff * diff;
        }
    }

    // wave-64 shuffle reduction
    #pragma unroll
    for (int off = 32; off > 0; off >>= 1)
        loss += __shfl_down(loss, off, 64);

    __shared__ float wsum[BDIM / 64];
    int lane = threadIdx.x & 63;
    int wid  = threadIdx.x >> 6;
    if (lane == 0) wsum[wid] = loss;
    __syncthreads();

    if (threadIdx.x == 0) {
        float s = 0.0f;
        #pragma unroll
        for (int w = 0; w < BDIM / 64; ++w) s += wsum[w];
        atomicAdd(out, s * inv_total);   // pre-scaled partial: sum stays O(1)
    }
}

extern "C" void kernel_launch(void* const* d_in, const int* in_sizes, int n_in,
                              void* d_out, int out_size, void* d_ws, size_t ws_size,
                              hipStream_t stream) {
    const float* depth = (const float*)d_in[0];
    const int*   xA    = (const int*)d_in[1];
    const int*   yA    = (const int*)d_in[2];
    const int*   xB    = (const int*)d_in[3];
    const int*   yB    = (const int*)d_in[4];
    const int*   ord   = (const int*)d_in[5];
    float* out = (float*)d_out;

    int total = in_sizes[1];                 // B*N = 3,200,000 (divisible by 8)
    int nthreads = total / UNROLL;           // 400,000
    float inv_total = 1.0f / (float)total;

    // d_out is poisoned to 0xAA before every timed launch — zero it first.
    rd_zero_kernel<<<1, 1, 0, stream>>>(out);

    int grid = (nthreads + BDIM - 1) / BDIM; // 1563 blocks
    rd_loss_kernel<<<grid, BDIM, 0, stream>>>(
        depth, xA, yA, xB, yB, ord, out, nthreads, inv_total);
}

// Round 3
// 264.680 us; speedup vs baseline: 1.3237x; 1.0941x over previous
//
#include <hip/hip_runtime.h>
#include <math.h>

// Problem constants (from reference): B=32, H=1024, W=1024, N=100000
#define RD_H 1024
#define RD_W 1024
#define RD_N 100000
#define BDIM 256
#define UNROLL 8        // N % 8 == 0 -> all 8 points of a thread share one batch index
#define NXCD 8
#define KPB  196        // blocks per XCD slice; 8*196=1568 blocks >= 1563 needed

__global__ void rd_zero_kernel(float* out) { out[0] = 0.0f; }

__global__ __launch_bounds__(BDIM) void rd_loss_kernel(
    const float* __restrict__ depth,   // (B, H, W) fp32
    const int*   __restrict__ xA,
    const int*   __restrict__ yA,
    const int*   __restrict__ xB,
    const int*   __restrict__ yB,
    const int*   __restrict__ ord,
    float* __restrict__ out,
    int total, float inv_total)
{
    // XCD-locality swizzle: blocks dispatch round-robin over 8 XCDs
    // (blockIdx%8 -> XCD). Remap so XCD x processes consecutive point ranges
    // in time order -> active image (4 MB) stays resident in that XCD's 4 MB L2.
    int v  = (blockIdx.x % NXCD) * KPB + (blockIdx.x / NXCD);
    int i0 = (v * BDIM + threadIdx.x) * UNROLL;

    float loss = 0.0f;
    if (i0 < total) {
        // All UNROLL consecutive points share one batch (RD_N % UNROLL == 0).
        int b = i0 / RD_N;
        const float* img = depth + (long)b * (RD_H * RD_W);

        // Vectorized, fully-coalesced index loads: 2x int4 per array.
        const int4* xA4 = (const int4*)(xA + i0);
        const int4* yA4 = (const int4*)(yA + i0);
        const int4* xB4 = (const int4*)(xB + i0);
        const int4* yB4 = (const int4*)(yB + i0);
        const int4* or4 = (const int4*)(ord + i0);
        int4 xa[2] = {xA4[0], xA4[1]};
        int4 ya[2] = {yA4[0], yA4[1]};
        int4 xb[2] = {xB4[0], xB4[1]};
        int4 yb[2] = {yB4[0], yB4[1]};
        int4 od[2] = {or4[0], or4[1]};

        const int* xap = (const int*)xa;
        const int* yap = (const int*)ya;
        const int* xbp = (const int*)xb;
        const int* ybp = (const int*)yb;
        const int* odp = (const int*)od;

        // Issue all 16 gathers before any use -> 16 loads in flight per thread.
        float za[UNROLL], zb[UNROLL];
        #pragma unroll
        for (int j = 0; j < UNROLL; ++j)
            za[j] = img[yap[j] * RD_W + xap[j]];
        #pragma unroll
        for (int j = 0; j < UNROLL; ++j)
            zb[j] = img[ybp[j] * RD_W + xbp[j]];

        #pragma unroll
        for (int j = 0; j < UNROLL; ++j) {
            float diff = za[j] - zb[j];
            float gt   = (float)(odp[j] - 1);   // {-1, 0, 1}
            float mask = fabsf(gt);             // {0, 1}
            // stable softplus(-gt*diff) = max(x,0) + log1p(exp(-|x|))
            float x  = -gt * diff;
            float sp = fmaxf(x, 0.0f) + log1pf(__expf(-fabsf(x)));
            loss += mask * sp + (1.0f - mask) * diff * diff;
        }
    }

    // wave-64 shuffle reduction
    #pragma unroll
    for (int off = 32; off > 0; off >>= 1)
        loss += __shfl_down(loss, off, 64);

    __shared__ float wsum[BDIM / 64];
    int lane = threadIdx.x & 63;
    int wid  = threadIdx.x >> 6;
    if (lane == 0) wsum[wid] = loss;
    __syncthreads();

    if (threadIdx.x == 0) {
        float s = 0.0f;
        #pragma unroll
        for (int w = 0; w < BDIM / 64; ++w) s += wsum[w];
        atomicAdd(out, s * inv_total);   // pre-scaled partial: sum stays O(1)
    }
}

extern "C" void kernel_launch(void* const* d_in, const int* in_sizes, int n_in,
                              void* d_out, int out_size, void* d_ws, size_t ws_size,
                              hipStream_t stream) {
    const float* depth = (const float*)d_in[0];
    const int*   xA    = (const int*)d_in[1];
    const int*   yA    = (const int*)d_in[2];
    const int*   xB    = (const int*)d_in[3];
    const int*   yB    = (const int*)d_in[4];
    const int*   ord   = (const int*)d_in[5];
    float* out = (float*)d_out;

    int total = in_sizes[1];                 // B*N = 3,200,000 (divisible by 8)
    float inv_total = 1.0f / (float)total;

    // d_out is poisoned to 0xAA before every timed launch — zero it first.
    rd_zero_kernel<<<1, 1, 0, stream>>>(out);

    rd_loss_kernel<<<NXCD * KPB, BDIM, 0, stream>>>(   // 1568 blocks
        depth, xA, yA, xB, yB, ord, out, total, inv_total);
}